// Round 1
// baseline (25379.790 us; speedup 1.0000x reference)
//
#include <hip/hip_runtime.h>

#define BATCH  131072
#define NSTEPS 100

// Constants from the reference
// SIGMA_X = 0.5, DT = 0.01, ALPHA = 1.0, sqrt_dt(f32) == 0.1f exactly
__device__ __forceinline__ void net_eval(
    float t, float y, bool isX, int lane,
    const float* __restrict__ W0, const float* __restrict__ b0,
    const float* __restrict__ W1, const float* __restrict__ b1,
    const float* __restrict__ W2, const float* __restrict__ b2,
    const float* __restrict__ W3, const float* __restrict__ b3,
    const float* __restrict__ W4, const float* __restrict__ b4,
    float (*act)[128],
    float& Y, float& dY)
{
    float cur[64];

    // ---- layer 0: input [t, y] (2-wide), tangent seed [0, 1] ----
    // x-lane out: sin(z),  v-lane out: cos(z) * W0[j,1]   (z = W0[j,0]*t + W0[j,1]*y + b0[j])
    for (int j = 0; j < 64; ++j) {
        float w0 = W0[2 * j];
        float w1 = W0[2 * j + 1];
        float z = fmaf(w0, t, fmaf(w1, y, b0[j]));
        float s, c;
        __sincosf(z, &s, &c);
        act[j][lane] = isX ? s : c * w1;
    }
    #pragma unroll
    for (int k = 0; k < 64; ++k) cur[k] = act[k][lane];

    // ---- hidden layers 1..3 (64x64, sine) ----
    #pragma unroll
    for (int l = 0; l < 3; ++l) {
        const float* __restrict__ W  = (l == 0) ? W1 : (l == 1) ? W2 : W3;
        const float* __restrict__ bb = (l == 0) ? b1 : (l == 1) ? b2 : b3;
        for (int j = 0; j < 64; ++j) {
            float m = 0.0f;
            #pragma unroll
            for (int k = 0; k < 64; ++k)
                m = fmaf(W[j * 64 + k], cur[k], m);
            // x-lane's pre-activation z is needed by BOTH lanes (v-lane needs cos(z))
            float mOther = __shfl_xor(m, 1);
            float zx = (isX ? m : mOther) + bb[j];
            float s, c;
            __sincosf(zx, &s, &c);
            act[j][lane] = isX ? s : c * m;   // x: sin(z) ; v: cos(z) * (W v)_j
        }
        #pragma unroll
        for (int k = 0; k < 64; ++k) cur[k] = act[k][lane];
    }

    // ---- output layer (1x64, linear) ----
    float acc = 0.0f;
    #pragma unroll
    for (int k = 0; k < 64; ++k) acc = fmaf(W4[k], cur[k], acc);
    float accP = __shfl_xor(acc, 1);
    float bl = b4[0];
    Y  = (isX ? acc : accP) + bl;   // Y from x-lane's dot
    dY = isX ? accP : acc;          // dY from v-lane's dot
}

extern "C" __global__ void __launch_bounds__(128, 2)
fbsnn_kernel(const float* __restrict__ W0, const float* __restrict__ b0,
             const float* __restrict__ W1, const float* __restrict__ b1,
             const float* __restrict__ W2, const float* __restrict__ b2,
             const float* __restrict__ W3, const float* __restrict__ b3,
             const float* __restrict__ W4, const float* __restrict__ b4,
             const float* __restrict__ y0p, const float* __restrict__ dW,
             float* __restrict__ out)
{
    __shared__ float act[64][128];   // per-lane scratch column; same-lane RW only, no barriers
    __shared__ float red[2];

    const int  tid    = threadIdx.x;
    const bool isX    = (tid & 1) == 0;
    const int  sample = blockIdx.x * 64 + (tid >> 1);

    const float SIG  = 0.5f;
    const float DT   = 0.01f;
    const float SQDT = 0.1f;   // np.float32(0.01)**0.5 rounds to 0.1f

    float y = y0p[0];
    float t = 0.0f;
    float Y0, dY0;
    net_eval(t, y, isX, tid, W0, b0, W1, b1, W2, b2, W3, b3, W4, b4, act, Y0, dY0);

    float loss = 0.0f;
    for (int s = 0; s < NSTEPS; ++s) {
        float dw  = dW[s * BATCH + sample];
        float Z0  = SIG * dY0;
        float q0  = -0.5f * Z0 / (SIG * SIG);
        float dws = dw * SQDT;
        float y1  = y + q0 * DT + SIG * dws;
        float t1  = t + DT;

        float Y1, dY1;
        net_eval(t1, y1, isX, tid, W0, b0, W1, b1, W2, b2, W3, b3, W4, b4, act, Y1, dY1);

        float Yt = Y0 - q0 * q0 * DT + Z0 * dws;
        float d  = Y1 - Yt;
        loss += d * d;

        t = t1; y = y1; Y0 = Y1; dY0 = dY1;
    }

    // terminal: (YN - yN^2)^2 + (dYN - 2*yN)^2   (ALPHA = 1)
    float d1 = Y0 - y * y;
    float d2 = dY0 - 2.0f * y;
    loss += d1 * d1 + d2 * d2;

    // both lanes of a pair computed identical loss -> weight 0.5; mean over BATCH
    loss *= 0.5f / (float)BATCH;

    // wave butterfly reduce (64 lanes), then block reduce, one atomic per block
    #pragma unroll
    for (int off = 1; off < 64; off <<= 1)
        loss += __shfl_xor(loss, off);
    if ((tid & 63) == 0) red[tid >> 6] = loss;
    __syncthreads();
    if (tid == 0) atomicAdd(out, red[0] + red[1]);
}

extern "C" void kernel_launch(void* const* d_in, const int* in_sizes, int n_in,
                              void* d_out, int out_size, void* d_ws, size_t ws_size,
                              hipStream_t stream) {
    const float* W0  = (const float*)d_in[0];
    const float* b0  = (const float*)d_in[1];
    const float* W1  = (const float*)d_in[2];
    const float* b1  = (const float*)d_in[3];
    const float* W2  = (const float*)d_in[4];
    const float* b2  = (const float*)d_in[5];
    const float* W3  = (const float*)d_in[6];
    const float* b3  = (const float*)d_in[7];
    const float* W4  = (const float*)d_in[8];
    const float* b4  = (const float*)d_in[9];
    const float* y0p = (const float*)d_in[10];
    const float* dW  = (const float*)d_in[11];
    float* out = (float*)d_out;

    hipMemsetAsync(d_out, 0, sizeof(float), stream);

    dim3 grid(BATCH / 64);   // 2048 blocks, 64 sample-pairs each
    dim3 block(128);
    fbsnn_kernel<<<grid, block, 0, stream>>>(W0, b0, W1, b1, W2, b2, W3, b3,
                                             W4, b4, y0p, dW, out);
}

// Round 2
// 20160.747 us; speedup vs baseline: 1.2589x; 1.2589x over previous
//
#include <hip/hip_runtime.h>

#define BATCH  131072
#define NSTEPS 100

// ---------------------------------------------------------------------------
// Prep: transpose weights into workspace so the main kernel's inner loop can
// s_load contiguous columns.
//   ws[0*4096 ..] = W1^T   (WT[k][j] = W1[j][k])
//   ws[1*4096 ..] = W2^T
//   ws[2*4096 ..] = W3^T
//   ws[3*4096 + k*64 + j] = W0[j][k]  (k=0,1)   -- layer-0 "columns"
// ---------------------------------------------------------------------------
extern "C" __global__ void prep_kernel(const float* __restrict__ W0,
                                       const float* __restrict__ W1,
                                       const float* __restrict__ W2,
                                       const float* __restrict__ W3,
                                       float* __restrict__ ws) {
    int j = threadIdx.x;   // 0..63  (output neuron)
    int k = blockIdx.x;    // 0..63  (input index)
    ws[0 * 4096 + k * 64 + j] = W1[j * 64 + k];
    ws[1 * 4096 + k * 64 + j] = W2[j * 64 + k];
    ws[2 * 4096 + k * 64 + j] = W3[j * 64 + k];
    if (k < 2) ws[3 * 4096 + k * 64 + j] = W0[j * 2 + k];
}

// ---------------------------------------------------------------------------
// Main kernel. Lane pair per sample: even lane = activations x, odd lane =
// tangent v (dY/dy path). act[j][lane] is a lane-private LDS column (no
// barriers, conflict-free: lane i -> bank i%32, 2-way aliasing is free).
// Matvec: acc[64] register accumulators (j fully unrolled, static indices ->
// guaranteed VGPRs, 64 independent FMA chains), k rolled (1 ds_read + 64
// uniform s_loads per iteration -> both pipes ~1/64 of FMA rate).
// ---------------------------------------------------------------------------
extern "C" __global__ void __launch_bounds__(128, 2)
fbsnn_kernel(const float* __restrict__ wsT,   // [3][64][64] + [2][64]
             const float* __restrict__ b0,
             const float* __restrict__ b1,
             const float* __restrict__ b2,
             const float* __restrict__ b3,
             const float* __restrict__ W4,
             const float* __restrict__ b4,
             const float* __restrict__ y0p,
             const float* __restrict__ dW,
             float* __restrict__ out)
{
    __shared__ float act[64][128];
    __shared__ float red[2];

    const int  tid    = threadIdx.x;
    const int  lane   = tid;
    const bool isX    = (tid & 1) == 0;
    const int  sample = blockIdx.x * 64 + (tid >> 1);

    const float SIG  = 0.5f;
    const float DT   = 0.01f;
    const float SQDT = 0.1f;   // np.float32(0.01)**0.5 == 0.1f exactly

    const float* __restrict__ WT0 = wsT + 3 * 4096;  // [2][64]

    float y = y0p[0];
    float t = 0.0f;
    float Y0 = 0.0f, dY0 = 0.0f;
    float loss = 0.0f;

    // step s = 0 evaluates net at (t0,y0); steps 1..100 advance then evaluate.
    for (int s = 0; s <= NSTEPS; ++s) {
        float q0 = 0.0f, Z0 = 0.0f, dws = 0.0f;
        if (s > 0) {
            float dw = dW[(s - 1) * BATCH + sample];
            Z0  = SIG * dY0;
            q0  = -0.5f * Z0 / (SIG * SIG);
            dws = dw * SQDT;
            y   = y + q0 * DT + SIG * dws;
            t   = t + DT;
        }

        // ---- layer 0: z_j = W0[j,0]*t + W0[j,1]*y + b0[j]; tangent seed [0,1]
        for (int j = 0; j < 64; ++j) {
            float w0 = WT0[j];
            float w1 = WT0[64 + j];
            float z = fmaf(w0, t, fmaf(w1, y, b0[j]));
            float sn, cs;
            __sincosf(z, &sn, &cs);
            act[j][lane] = isX ? sn : cs * w1;
        }

        // ---- hidden layers 1..3 ----
        for (int l = 0; l < 3; ++l) {
            const float* __restrict__ WT = wsT + l * 4096;
            const float* __restrict__ bb = (l == 0) ? b1 : (l == 1) ? b2 : b3;

            float acc[64];
            #pragma unroll
            for (int j = 0; j < 64; ++j) acc[j] = 0.0f;

            float xk = act[0][lane];
            for (int k = 0; k < 64; ++k) {
                float xn = act[(k + 1) & 63][lane];   // prefetch next
                const float* __restrict__ wc = WT + k * 64;
                #pragma unroll
                for (int j = 0; j < 64; ++j)
                    acc[j] = fmaf(wc[j], xk, acc[j]);
                xk = xn;
            }

            // epilogue: bias + sine (x path) / cos(z)*(Wv) (tangent path)
            #pragma unroll
            for (int j = 0; j < 64; ++j) {
                float m  = acc[j];
                float mO = __shfl_xor(m, 1);
                float zx = (isX ? m : mO) + bb[j];
                float sn, cs;
                __sincosf(zx, &sn, &cs);
                act[j][lane] = isX ? sn : cs * m;
            }
        }

        // ---- output layer: dot(W4, act) + b4 ----
        float a0 = 0.f, a1 = 0.f, a2 = 0.f, a3 = 0.f;
        for (int k = 0; k < 64; k += 4) {
            a0 = fmaf(W4[k + 0], act[k + 0][lane], a0);
            a1 = fmaf(W4[k + 1], act[k + 1][lane], a1);
            a2 = fmaf(W4[k + 2], act[k + 2][lane], a2);
            a3 = fmaf(W4[k + 3], act[k + 3][lane], a3);
        }
        float acc  = (a0 + a1) + (a2 + a3);
        float accP = __shfl_xor(acc, 1);
        float Y1  = (isX ? acc : accP) + b4[0];
        float dY1 = isX ? accP : acc;

        if (s > 0) {
            float Yt = Y0 - q0 * q0 * DT + Z0 * dws;
            float d  = Y1 - Yt;
            loss += d * d;
        }
        Y0 = Y1; dY0 = dY1;
    }

    // terminal: (YN - yN^2)^2 + (dYN - 2*yN)^2   (ALPHA = 1)
    float d1 = Y0 - y * y;
    float d2 = dY0 - 2.0f * y;
    loss += d1 * d1 + d2 * d2;

    // both lanes of a pair computed identical loss -> weight 0.5; mean over B
    loss *= 0.5f / (float)BATCH;

    #pragma unroll
    for (int off = 1; off < 64; off <<= 1)
        loss += __shfl_xor(loss, off);
    if ((tid & 63) == 0) red[tid >> 6] = loss;
    __syncthreads();
    if (tid == 0) atomicAdd(out, red[0] + red[1]);
}

extern "C" void kernel_launch(void* const* d_in, const int* in_sizes, int n_in,
                              void* d_out, int out_size, void* d_ws, size_t ws_size,
                              hipStream_t stream) {
    const float* W0  = (const float*)d_in[0];
    const float* b0  = (const float*)d_in[1];
    const float* W1  = (const float*)d_in[2];
    const float* b1  = (const float*)d_in[3];
    const float* W2  = (const float*)d_in[4];
    const float* b2  = (const float*)d_in[5];
    const float* W3  = (const float*)d_in[6];
    const float* b3  = (const float*)d_in[7];
    const float* W4  = (const float*)d_in[8];
    const float* b4  = (const float*)d_in[9];
    const float* y0p = (const float*)d_in[10];
    const float* dW  = (const float*)d_in[11];
    float* out = (float*)d_out;
    float* wsT = (float*)d_ws;

    hipMemsetAsync(d_out, 0, sizeof(float), stream);

    prep_kernel<<<dim3(64), dim3(64), 0, stream>>>(W0, W1, W2, W3, wsT);

    dim3 grid(BATCH / 64);   // 2048 blocks, 64 sample-pairs each
    dim3 block(128);
    fbsnn_kernel<<<grid, block, 0, stream>>>(wsT, b0, b1, b2, b3, W4, b4,
                                             y0p, dW, out);
}

// Round 3
// 6892.474 us; speedup vs baseline: 3.6822x; 2.9250x over previous
//
#include <hip/hip_runtime.h>

#define BATCH  131072
#define NSTEPS 100

// ---------------------------------------------------------------------------
// Prep: transpose hidden weights so the GEMM k-loop reads contiguous columns.
//   ws[l*4096 + k*64 + j] = W_{l+1}[j][k]   (l = 0,1,2)
//   ws[12288 + k*64 + j]  = W0[j][k]        (k = 0,1)
// ---------------------------------------------------------------------------
extern "C" __global__ void prep_kernel(const float* __restrict__ W0,
                                       const float* __restrict__ W1,
                                       const float* __restrict__ W2,
                                       const float* __restrict__ W3,
                                       float* __restrict__ ws) {
    int j = threadIdx.x;   // output neuron
    int k = blockIdx.x;    // input index
    ws[0 * 4096 + k * 64 + j] = W1[j * 64 + k];
    ws[1 * 4096 + k * 64 + j] = W2[j * 64 + k];
    ws[2 * 4096 + k * 64 + j] = W3[j * 64 + k];
    if (k < 2) ws[12288 + k * 64 + j] = W0[j * 2 + k];
}

// ---------------------------------------------------------------------------
// Block GEMM formulation. Block = 4 waves, 64 samples -> A[64 neurons][128
// cols] in LDS, cols interleaved (2l = x-path, 2l+1 = tangent v-path).
// Wave w computes neurons 16w..16w+15 for ALL columns; lane l carries the
// x,v pair of sample l. Per k: 1 ds_read_b64 + 16 scalar weight loads
// (wave-uniform via readfirstlane) -> 32 FMAs. Each wave redundantly tracks
// its lane's sample trajectory (cheap; avoids all cross-wave state).
// ---------------------------------------------------------------------------
extern "C" __global__ void __launch_bounds__(256, 4)
fbsnn_kernel(const float* __restrict__ wsT,
             const float* __restrict__ b0,
             const float* __restrict__ b1,
             const float* __restrict__ b2,
             const float* __restrict__ b3,
             const float* __restrict__ W4,
             const float* __restrict__ b4,
             const float* __restrict__ y0p,
             const float* __restrict__ dW,
             float* __restrict__ out)
{
    __shared__ float A[64][128];   // 32 KB

    const int tid = threadIdx.x;
    const int l   = tid & 63;                                    // lane = sample
    const int w   = __builtin_amdgcn_readfirstlane(tid >> 6);    // wave id (uniform)
    const int sample = blockIdx.x * 64 + l;

    const float SIG  = 0.5f;
    const float DT   = 0.01f;
    const float SQDT = 0.1f;   // np.float32(0.01)**0.5 == 0.1f

    const float* __restrict__ w0c = wsT + 12288;        // W0 col 0 (t-weights)
    const float* __restrict__ w1c = wsT + 12288 + 64;   // W0 col 1 (y-weights)

    float y = y0p[0];
    float t = 0.0f;
    float Y0 = 0.0f, dY0 = 0.0f;
    float loss = 0.0f;

    for (int s = 0; s <= NSTEPS; ++s) {
        float q0 = 0.0f, Z0 = 0.0f, dws = 0.0f;
        if (s > 0) {
            float dw = dW[(s - 1) * BATCH + sample];
            Z0  = SIG * dY0;
            q0  = -0.5f * Z0 / (SIG * SIG);
            dws = dw * SQDT;
            y   = y + q0 * DT + SIG * dws;
            t   = t + DT;
        }

        // ---- layer 0: A[n][2l] = sin(z), A[n][2l+1] = cos(z)*W0[n][1] ----
        // (previous step's readers finished at the barrier closing last step)
        #pragma unroll
        for (int j = 0; j < 16; ++j) {
            int n = w * 16 + j;                      // uniform
            float wa = w0c[n], wb = w1c[n];          // scalar loads
            float z = fmaf(wa, t, fmaf(wb, y, b0[n]));
            float sn, cs;
            __sincosf(z, &sn, &cs);
            float2 o; o.x = sn; o.y = cs * wb;
            *reinterpret_cast<float2*>(&A[n][2 * l]) = o;
        }
        __syncthreads();                             // A0 ready

        // ---- hidden layers 1..3 ----
        for (int li = 0; li < 3; ++li) {
            const float* __restrict__ Wl =
                wsT + li * 4096 + w * 16;            // uniform base
            const float* __restrict__ bb =
                (li == 0) ? b1 : (li == 1) ? b2 : b3;

            float accx[16], accv[16];
            #pragma unroll
            for (int j = 0; j < 16; ++j) { accx[j] = 0.0f; accv[j] = 0.0f; }

            #pragma unroll 2
            for (int k = 0; k < 64; ++k) {
                float2 a = *reinterpret_cast<const float2*>(&A[k][2 * l]);
                #pragma unroll
                for (int j = 0; j < 16; ++j) {
                    float wv = Wl[k * 64 + j];       // wave-uniform -> s_load
                    accx[j] = fmaf(wv, a.x, accx[j]);
                    accv[j] = fmaf(wv, a.y, accv[j]);
                }
            }
            __syncthreads();                         // all GEMM reads done

            #pragma unroll
            for (int j = 0; j < 16; ++j) {
                int n = w * 16 + j;
                float zx = accx[j] + bb[n];
                float sn, cs;
                __sincosf(zx, &sn, &cs);
                float2 o; o.x = sn; o.y = cs * accv[j];
                *reinterpret_cast<float2*>(&A[n][2 * l]) = o;
            }
            __syncthreads();                         // A_{li+1} ready
        }

        // ---- output layer: Y = W4 . a + b4 ; dY = W4 . v ----
        float dx0 = 0.f, dx1 = 0.f, dv0 = 0.f, dv1 = 0.f;
        #pragma unroll 4
        for (int k = 0; k < 64; k += 2) {
            float2 a0 = *reinterpret_cast<const float2*>(&A[k][2 * l]);
            float2 a1 = *reinterpret_cast<const float2*>(&A[k + 1][2 * l]);
            dx0 = fmaf(W4[k], a0.x, dx0);
            dv0 = fmaf(W4[k], a0.y, dv0);
            dx1 = fmaf(W4[k + 1], a1.x, dx1);
            dv1 = fmaf(W4[k + 1], a1.y, dv1);
        }
        float Y1  = (dx0 + dx1) + b4[0];
        float dY1 = dv0 + dv1;

        if (s > 0) {
            float Yt = Y0 - q0 * q0 * DT + Z0 * dws;
            float d  = Y1 - Yt;
            loss += d * d;
        }
        Y0 = Y1; dY0 = dY1;
        __syncthreads();   // output reads done before next step's L0 writes
    }

    // terminal: (YN - yN^2)^2 + (dYN - 2*yN)^2   (ALPHA = 1)
    float d1 = Y0 - y * y;
    float d2 = dY0 - 2.0f * y;
    loss += d1 * d1 + d2 * d2;

    loss *= 1.0f / (float)BATCH;

    // all 4 waves hold identical per-lane losses; reduce wave 0 only
    if (tid < 64) {
        #pragma unroll
        for (int off = 1; off < 64; off <<= 1)
            loss += __shfl_xor(loss, off);
        if (tid == 0) atomicAdd(out, loss);
    }
}

extern "C" void kernel_launch(void* const* d_in, const int* in_sizes, int n_in,
                              void* d_out, int out_size, void* d_ws, size_t ws_size,
                              hipStream_t stream) {
    const float* W0  = (const float*)d_in[0];
    const float* b0  = (const float*)d_in[1];
    const float* W1  = (const float*)d_in[2];
    const float* b1  = (const float*)d_in[3];
    const float* W2  = (const float*)d_in[4];
    const float* b2  = (const float*)d_in[5];
    const float* W3  = (const float*)d_in[6];
    const float* b3  = (const float*)d_in[7];
    const float* W4  = (const float*)d_in[8];
    const float* b4  = (const float*)d_in[9];
    const float* y0p = (const float*)d_in[10];
    const float* dW  = (const float*)d_in[11];
    float* out = (float*)d_out;
    float* wsT = (float*)d_ws;

    hipMemsetAsync(d_out, 0, sizeof(float), stream);

    prep_kernel<<<dim3(64), dim3(64), 0, stream>>>(W0, W1, W2, W3, wsT);

    dim3 grid(BATCH / 64);   // 2048 blocks x 64 samples
    dim3 block(256);
    fbsnn_kernel<<<grid, block, 0, stream>>>(wsT, b0, b1, b2, b3, W4, b4,
                                             y0p, dW, out);
}

// Round 4
// 1178.599 us; speedup vs baseline: 21.5339x; 5.8480x over previous
//
#include <hip/hip_runtime.h>

#define BATCH  131072
#define NSTEPS 100

typedef _Float16 half8 __attribute__((ext_vector_type(8)));
typedef _Float16 half4 __attribute__((ext_vector_type(4)));
typedef float    f32x4 __attribute__((ext_vector_type(4)));

// ---------------------------------------------------------------------------
// MFMA formulation. Block = 4 waves = 64 samples.
// Activations X^T[col][neuron] f16 in LDS, XOR-swizzled (byte ^= (col&7)<<4).
//   cols 0..63  = x-path (sample l -> row l)
//   cols 64..127= v-path (tangent)
// Wave w owns output-neuron stripe [16w,16w+16). GEMM per layer =
// 16 x mfma_f32_16x16x32_f16 (8 col-tiles x 2 k-tiles). A-fragments (weights)
// converted fp32->f16 once at start, persistent in VGPRs. C layout
// (col=lane&15, row=(lane>>4)*4+reg) puts x-tile t and v-tile t+4 outputs for
// the same (neuron, sample) in the SAME lane -> shuffle-free sine epilogue.
// Layer-3 epilogue folds the W4 dot: butterfly over k-groups + cross-wave
// partials in LDS. 4 barriers/step, ping-pong X buffers (L0->b0, L1->b1,
// L2->b0, L3 reads b0).
// ---------------------------------------------------------------------------
extern "C" __global__ void __launch_bounds__(256, 4)
fbsnn_kernel(const float* __restrict__ W0, const float* __restrict__ b0,
             const float* __restrict__ W1, const float* __restrict__ b1,
             const float* __restrict__ W2, const float* __restrict__ b2,
             const float* __restrict__ W3, const float* __restrict__ b3,
             const float* __restrict__ W4, const float* __restrict__ b4,
             const float* __restrict__ y0p, const float* __restrict__ dW,
             float* __restrict__ out)
{
    __shared__ _Float16 X[2][8192];   // two 128x64 f16 buffers, 16 KB each
    __shared__ float part[8][64];     // [wave*2 + (0:x,1:v)][sample]

    const int tid = threadIdx.x;
    const int l   = tid & 63;
    const int wu  = __builtin_amdgcn_readfirstlane(tid >> 6);
    const int i   = l & 15;           // C col / A,B row selector
    const int g   = l >> 4;           // k-group
    const int sample = blockIdx.x * 64 + l;

    const float SIG = 0.5f, DT = 0.01f, SQDT = 0.1f;

    // ---- persistent A fragments: W[m][k], m = 16*wu + i, k = kt*32 + g*8 + e
    half8 afr[3][2];
    const float* Wsrc[3] = {W1, W2, W3};
    #pragma unroll
    for (int li = 0; li < 3; ++li)
        #pragma unroll
        for (int kt = 0; kt < 2; ++kt) {
            const float* wr = Wsrc[li] + (16 * wu + i) * 64 + kt * 32 + g * 8;
            #pragma unroll
            for (int e = 0; e < 8; ++e) afr[li][kt][e] = (_Float16)wr[e];
        }

    // ---- per-lane epilogue constants: C rows m = mrow..mrow+3
    const int mrow = 16 * wu + 4 * g;
    float bias[3][4], W4l[4];
    const float* bsrc[3] = {b1, b2, b3};
    #pragma unroll
    for (int li = 0; li < 3; ++li)
        #pragma unroll
        for (int r = 0; r < 4; ++r) bias[li][r] = bsrc[li][mrow + r];
    #pragma unroll
    for (int r = 0; r < 4; ++r) W4l[r] = W4[mrow + r];
    const float b4v = b4[0];

    // ---- swizzled LDS byte-address bases (constant per lane) ----
    const int swz  = (i & 7) << 4;
    const int rb0  = i * 128 + ((16 * g) ^ swz);          // B k-tile 0
    const int rb1  = i * 128 + ((64 + 16 * g) ^ swz);     // B k-tile 1
    const int wbx  = i * 128 + ((32 * wu + 8 * g) ^ swz); // epilogue write
    const int swz0 = (l & 7) << 4;
    const int l0a  = l * 128 + ((32 * wu) ^ swz0);        // L0 write lo
    const int l0b  = l * 128 + ((32 * wu + 16) ^ swz0);   // L0 write hi

    float y = y0p[0];
    float t = 0.0f;
    float Y0 = 0.f, dY0 = 0.f, q0 = 0.f, Z0 = 0.f, dws = 0.f, loss = 0.f;

    for (int s = 0; s <= NSTEPS; ++s) {
        // ================= layer 0 -> X[0] =================
        {
            half8 xlo, xhi, vlo, vhi;
            #pragma unroll
            for (int j = 0; j < 16; ++j) {
                int n = 16 * wu + j;                       // uniform -> s_load
                float wa = W0[2 * n], wb = W0[2 * n + 1];
                float z = fmaf(wa, t, fmaf(wb, y, b0[n]));
                float sn, cs;
                __sincosf(z, &sn, &cs);
                _Float16 xv = (_Float16)sn;
                _Float16 vv = (_Float16)(cs * wb);
                if (j < 8) { xlo[j] = xv; vlo[j] = vv; }
                else       { xhi[j - 8] = xv; vhi[j - 8] = vv; }
            }
            char* Xb = (char*)&X[0][0];
            *(half8*)(Xb + l0a) = xlo;
            *(half8*)(Xb + l0b) = xhi;
            *(half8*)(Xb + 8192 + l0a) = vlo;
            *(half8*)(Xb + 8192 + l0b) = vhi;
        }
        __syncthreads();

        f32x4 ax[4], av[4];

        // ================= layers 1..3 =================
        #pragma unroll
        for (int li = 0; li < 3; ++li) {
            const char* Xr = (const char*)&X[li & 1][0];   // 0,1,0
            #pragma unroll
            for (int tt = 0; tt < 4; ++tt) {
                half8 bx0 = *(const half8*)(Xr + rb0 + tt * 2048);
                half8 bx1 = *(const half8*)(Xr + rb1 + tt * 2048);
                f32x4 a = {0.f, 0.f, 0.f, 0.f};
                a = __builtin_amdgcn_mfma_f32_16x16x32_f16(afr[li][0], bx0, a, 0, 0, 0);
                a = __builtin_amdgcn_mfma_f32_16x16x32_f16(afr[li][1], bx1, a, 0, 0, 0);
                ax[tt] = a;
                half8 bv0 = *(const half8*)(Xr + 8192 + rb0 + tt * 2048);
                half8 bv1 = *(const half8*)(Xr + 8192 + rb1 + tt * 2048);
                f32x4 v = {0.f, 0.f, 0.f, 0.f};
                v = __builtin_amdgcn_mfma_f32_16x16x32_f16(afr[li][0], bv0, v, 0, 0, 0);
                v = __builtin_amdgcn_mfma_f32_16x16x32_f16(afr[li][1], bv1, v, 0, 0, 0);
                av[tt] = v;
            }

            if (li < 2) {
                // epilogue: sine + tangent, write X[(li+1)&1]
                char* Xw = (char*)&X[(li + 1) & 1][0];
                #pragma unroll
                for (int tt = 0; tt < 4; ++tt) {
                    half4 xo, vo;
                    #pragma unroll
                    for (int r = 0; r < 4; ++r) {
                        float zx = ax[tt][r] + bias[li][r];
                        float sn, cs;
                        __sincosf(zx, &sn, &cs);
                        xo[r] = (_Float16)sn;
                        vo[r] = (_Float16)(cs * av[tt][r]);
                    }
                    *(half4*)(Xw + wbx + tt * 2048) = xo;
                    *(half4*)(Xw + 8192 + wbx + tt * 2048) = vo;
                }
            } else {
                // layer-3 epilogue: fold W4 dot, cross-lane + cross-wave reduce
                #pragma unroll
                for (int tt = 0; tt < 4; ++tt) {
                    float sx = 0.f, sv = 0.f;
                    #pragma unroll
                    for (int r = 0; r < 4; ++r) {
                        float zx = ax[tt][r] + bias[2][r];
                        float sn, cs;
                        __sincosf(zx, &sn, &cs);
                        sx = fmaf(W4l[r], sn, sx);
                        sv = fmaf(W4l[r], cs * av[tt][r], sv);
                    }
                    sx += __shfl_xor(sx, 16); sx += __shfl_xor(sx, 32);
                    sv += __shfl_xor(sv, 16); sv += __shfl_xor(sv, 32);
                    if (l < 16) {
                        part[2 * wu][16 * tt + l]     = sx;
                        part[2 * wu + 1][16 * tt + l] = sv;
                    }
                }
            }
            __syncthreads();
        }

        // ================= trajectory / loss =================
        float Y1  = ((part[0][l] + part[2][l]) + (part[4][l] + part[6][l])) + b4v;
        float dY1 = (part[1][l] + part[3][l]) + (part[5][l] + part[7][l]);

        if (s > 0) {
            float Yt = Y0 - q0 * q0 * DT + Z0 * dws;
            float d  = Y1 - Yt;
            loss += d * d;
        }
        Y0 = Y1; dY0 = dY1;
        if (s < NSTEPS) {
            float dwv = dW[s * BATCH + sample];
            Z0  = SIG * dY0;
            q0  = -0.5f * Z0 / (SIG * SIG);
            dws = dwv * SQDT;
            y   = y + q0 * DT + SIG * dws;
            t   = t + DT;
        }
        // next L0 writes X[0]: G3's reads of X[0] were before the last barrier ✓
    }

    // terminal: (YN - yN^2)^2 + (dYN - 2*yN)^2
    float d1 = Y0 - y * y;
    float d2 = dY0 - 2.0f * y;
    loss += d1 * d1 + d2 * d2;

    if (tid < 64) {   // all waves hold identical loss; reduce wave 0 only
        #pragma unroll
        for (int off = 1; off < 64; off <<= 1)
            loss += __shfl_xor(loss, off);
        if (tid == 0) atomicAdd(out, loss / (float)BATCH);
    }
}

extern "C" void kernel_launch(void* const* d_in, const int* in_sizes, int n_in,
                              void* d_out, int out_size, void* d_ws, size_t ws_size,
                              hipStream_t stream) {
    const float* W0  = (const float*)d_in[0];
    const float* b0  = (const float*)d_in[1];
    const float* W1  = (const float*)d_in[2];
    const float* b1  = (const float*)d_in[3];
    const float* W2  = (const float*)d_in[4];
    const float* b2  = (const float*)d_in[5];
    const float* W3  = (const float*)d_in[6];
    const float* b3  = (const float*)d_in[7];
    const float* W4  = (const float*)d_in[8];
    const float* b4  = (const float*)d_in[9];
    const float* y0p = (const float*)d_in[10];
    const float* dW  = (const float*)d_in[11];
    float* out = (float*)d_out;

    hipMemsetAsync(d_out, 0, sizeof(float), stream);

    dim3 grid(BATCH / 64);   // 2048 blocks x 64 samples
    dim3 block(256);
    fbsnn_kernel<<<grid, block, 0, stream>>>(W0, b0, W1, b1, W2, b2, W3, b3,
                                             W4, b4, y0p, dW, out);
}

// Round 5
// 1104.256 us; speedup vs baseline: 22.9836x; 1.0673x over previous
//
#include <hip/hip_runtime.h>

#define BATCH  131072
#define NSTEPS 100

typedef _Float16 half8 __attribute__((ext_vector_type(8)));
typedef float    f32x4 __attribute__((ext_vector_type(4)));
typedef unsigned int u32x2 __attribute__((ext_vector_type(2)));
typedef unsigned int u32x4 __attribute__((ext_vector_type(4)));

// ---------------------------------------------------------------------------
// MFMA formulation (round-4 structure) + VALU cuts:
//  - bias folded into MFMA C-init (D = W.x + bias directly)
//  - all f32->f16 conversion via v_cvt_pkrtz_f16_f32 (packed, full-rate)
//  - part[] aliased into X[1] (dead there) -> LDS 32768 -> 5 blocks/CU
//  - q0 = -dY0 (exact: power-of-2 constants), divide removed
//  - dW prefetched at step start (hidden under 4 barriers of compute)
// Block = 4 waves = 64 samples. X^T[col][neuron] f16 in LDS, XOR-swizzled.
// Wave w owns neuron stripe [16w,16w+16); lane l carries sample l.
// ---------------------------------------------------------------------------
extern "C" __global__ void __launch_bounds__(256, 5)
fbsnn_kernel(const float* __restrict__ W0, const float* __restrict__ b0,
             const float* __restrict__ W1, const float* __restrict__ b1,
             const float* __restrict__ W2, const float* __restrict__ b2,
             const float* __restrict__ W3, const float* __restrict__ b3,
             const float* __restrict__ W4, const float* __restrict__ b4,
             const float* __restrict__ y0p, const float* __restrict__ dW,
             float* __restrict__ out)
{
    __shared__ _Float16 X[2][8192];          // 32 KB total (two 16 KB buffers)
    float* part = (float*)&X[1][0];          // 2 KB alias; X[1] dead during li=2

    const int tid = threadIdx.x;
    const int l   = tid & 63;
    const int wu  = __builtin_amdgcn_readfirstlane(tid >> 6);
    const int i   = l & 15;           // C col / B row selector
    const int g   = l >> 4;           // k-group
    const int sample = blockIdx.x * 64 + l;

    const float DT = 0.01f, SQDT = 0.1f;

    // persistent A fragments: W[m][k], m = 16*wu + i, k = kt*32 + g*8 + e
    half8 afr[3][2];
    const float* Wsrc[3] = {W1, W2, W3};
    #pragma unroll
    for (int li = 0; li < 3; ++li)
        #pragma unroll
        for (int kt = 0; kt < 2; ++kt) {
            const float* wr = Wsrc[li] + (16 * wu + i) * 64 + kt * 32 + g * 8;
            #pragma unroll
            for (int e = 0; e < 8; ++e) afr[li][kt][e] = (_Float16)wr[e];
        }

    // per-lane epilogue constants: C rows m = mrow..mrow+3
    const int mrow = 16 * wu + 4 * g;
    float bias[3][4], W4l[4];
    const float* bsrc[3] = {b1, b2, b3};
    #pragma unroll
    for (int li = 0; li < 3; ++li)
        #pragma unroll
        for (int r = 0; r < 4; ++r) bias[li][r] = bsrc[li][mrow + r];
    #pragma unroll
    for (int r = 0; r < 4; ++r) W4l[r] = W4[mrow + r];
    const float b4v = b4[0];

    // swizzled LDS byte-address bases (constant per lane)
    const int swz  = (i & 7) << 4;
    const int rb0  = i * 128 + ((16 * g) ^ swz);          // B k-tile 0
    const int rb1  = i * 128 + ((64 + 16 * g) ^ swz);     // B k-tile 1
    const int wbx  = i * 128 + ((32 * wu + 8 * g) ^ swz); // epilogue write
    const int swz0 = (l & 7) << 4;
    const int l0a  = l * 128 + ((32 * wu) ^ swz0);        // L0 write lo
    const int l0b  = l * 128 + ((32 * wu + 16) ^ swz0);   // L0 write hi

    float y = y0p[0];
    float t = 0.0f;
    float Y0 = 0.f, dY0 = 0.f, q0 = 0.f, Z0 = 0.f, dws = 0.f, loss = 0.f;

    for (int s = 0; s <= NSTEPS; ++s) {
        float dwv = 0.0f;
        if (s < NSTEPS) dwv = dW[s * BATCH + sample];   // prefetch early

        // ================= layer 0 -> X[0] =================
        {
            u32x4 xlo, xhi, vlo, vhi;
            #pragma unroll
            for (int jj = 0; jj < 8; ++jj) {
                int n0 = 16 * wu + 2 * jj;
                float wa0 = W0[2 * n0 + 0], wb0 = W0[2 * n0 + 1];
                float wa1 = W0[2 * n0 + 2], wb1 = W0[2 * n0 + 3];
                float z0 = fmaf(wa0, t, fmaf(wb0, y, b0[n0 + 0]));
                float z1 = fmaf(wa1, t, fmaf(wb1, y, b0[n0 + 1]));
                float s0, c0, s1, c1;
                __sincosf(z0, &s0, &c0);
                __sincosf(z1, &s1, &c1);
                unsigned xs = __builtin_bit_cast(unsigned, __builtin_amdgcn_cvt_pkrtz(s0, s1));
                unsigned vs = __builtin_bit_cast(unsigned, __builtin_amdgcn_cvt_pkrtz(c0 * wb0, c1 * wb1));
                if (jj < 4) { xlo[jj] = xs; vlo[jj] = vs; }
                else        { xhi[jj - 4] = xs; vhi[jj - 4] = vs; }
            }
            char* Xb = (char*)&X[0][0];
            *(u32x4*)(Xb + l0a)        = xlo;
            *(u32x4*)(Xb + l0b)        = xhi;
            *(u32x4*)(Xb + 8192 + l0a) = vlo;
            *(u32x4*)(Xb + 8192 + l0b) = vhi;
        }
        __syncthreads();

        // ================= layers 1..3 =================
        #pragma unroll
        for (int li = 0; li < 3; ++li) {
            const char* Xr = (const char*)&X[li & 1][0];   // 0,1,0
            f32x4 ax[4], av[4];
            #pragma unroll
            for (int tt = 0; tt < 4; ++tt) {
                half8 bx0 = *(const half8*)(Xr + rb0 + tt * 2048);
                half8 bx1 = *(const half8*)(Xr + rb1 + tt * 2048);
                f32x4 a = {bias[li][0], bias[li][1], bias[li][2], bias[li][3]};
                a = __builtin_amdgcn_mfma_f32_16x16x32_f16(afr[li][0], bx0, a, 0, 0, 0);
                a = __builtin_amdgcn_mfma_f32_16x16x32_f16(afr[li][1], bx1, a, 0, 0, 0);
                ax[tt] = a;
                half8 bv0 = *(const half8*)(Xr + 8192 + rb0 + tt * 2048);
                half8 bv1 = *(const half8*)(Xr + 8192 + rb1 + tt * 2048);
                f32x4 v = {0.f, 0.f, 0.f, 0.f};
                v = __builtin_amdgcn_mfma_f32_16x16x32_f16(afr[li][0], bv0, v, 0, 0, 0);
                v = __builtin_amdgcn_mfma_f32_16x16x32_f16(afr[li][1], bv1, v, 0, 0, 0);
                av[tt] = v;
            }

            if (li < 2) {
                char* Xw = (char*)&X[(li + 1) & 1][0];
                #pragma unroll
                for (int tt = 0; tt < 4; ++tt) {
                    float sn0, cs0, sn1, cs1, sn2, cs2, sn3, cs3;
                    __sincosf(ax[tt][0], &sn0, &cs0);
                    __sincosf(ax[tt][1], &sn1, &cs1);
                    __sincosf(ax[tt][2], &sn2, &cs2);
                    __sincosf(ax[tt][3], &sn3, &cs3);
                    u32x2 xo, vo;
                    xo[0] = __builtin_bit_cast(unsigned, __builtin_amdgcn_cvt_pkrtz(sn0, sn1));
                    xo[1] = __builtin_bit_cast(unsigned, __builtin_amdgcn_cvt_pkrtz(sn2, sn3));
                    vo[0] = __builtin_bit_cast(unsigned, __builtin_amdgcn_cvt_pkrtz(cs0 * av[tt][0], cs1 * av[tt][1]));
                    vo[1] = __builtin_bit_cast(unsigned, __builtin_amdgcn_cvt_pkrtz(cs2 * av[tt][2], cs3 * av[tt][3]));
                    *(u32x2*)(Xw + wbx + tt * 2048)        = xo;
                    *(u32x2*)(Xw + 8192 + wbx + tt * 2048) = vo;
                }
            } else {
                // layer-3 epilogue: fold W4 dot, cross-lane + cross-wave reduce
                #pragma unroll
                for (int tt = 0; tt < 4; ++tt) {
                    float sx = 0.f, sv = 0.f;
                    #pragma unroll
                    for (int r = 0; r < 4; ++r) {
                        float sn, cs;
                        __sincosf(ax[tt][r], &sn, &cs);
                        sx = fmaf(W4l[r], sn, sx);
                        sv = fmaf(W4l[r], cs * av[tt][r], sv);
                    }
                    sx += __shfl_xor(sx, 16); sx += __shfl_xor(sx, 32);
                    sv += __shfl_xor(sv, 16); sv += __shfl_xor(sv, 32);
                    if (l < 16) {
                        part[128 * wu + 16 * tt + l]      = sx;
                        part[128 * wu + 64 + 16 * tt + l] = sv;
                    }
                }
            }
            __syncthreads();
        }

        // ================= trajectory / loss =================
        float Y1  = ((part[l] + part[128 + l]) + (part[256 + l] + part[384 + l])) + b4v;
        float dY1 = ((part[64 + l] + part[192 + l]) + (part[320 + l] + part[448 + l]));

        if (s > 0) {
            float Yt = Y0 - q0 * q0 * DT + Z0 * dws;
            float d  = Y1 - Yt;
            loss += d * d;
        }
        Y0 = Y1; dY0 = dY1;
        if (s < NSTEPS) {
            Z0  = 0.5f * dY0;       // SIG * dY0
            q0  = -dY0;             // -0.5*Z0/SIG^2, exact (powers of 2)
            dws = dwv * SQDT;
            y   = y + q0 * DT + 0.5f * dws;
            t   = t + DT;
        }
        // next L0 writes X[0]; X[1]/part readers all passed the last barrier ✓
    }

    // terminal: (YN - yN^2)^2 + (dYN - 2*yN)^2
    float d1 = Y0 - y * y;
    float d2 = dY0 - 2.0f * y;
    loss += d1 * d1 + d2 * d2;

    if (tid < 64) {   // all waves hold identical loss; reduce wave 0 only
        #pragma unroll
        for (int off = 1; off < 64; off <<= 1)
            loss += __shfl_xor(loss, off);
        if (tid == 0) atomicAdd(out, loss / (float)BATCH);
    }
}

extern "C" void kernel_launch(void* const* d_in, const int* in_sizes, int n_in,
                              void* d_out, int out_size, void* d_ws, size_t ws_size,
                              hipStream_t stream) {
    const float* W0  = (const float*)d_in[0];
    const float* b0  = (const float*)d_in[1];
    const float* W1  = (const float*)d_in[2];
    const float* b1  = (const float*)d_in[3];
    const float* W2  = (const float*)d_in[4];
    const float* b2  = (const float*)d_in[5];
    const float* W3  = (const float*)d_in[6];
    const float* b3  = (const float*)d_in[7];
    const float* W4  = (const float*)d_in[8];
    const float* b4  = (const float*)d_in[9];
    const float* y0p = (const float*)d_in[10];
    const float* dW  = (const float*)d_in[11];
    float* out = (float*)d_out;

    hipMemsetAsync(d_out, 0, sizeof(float), stream);

    dim3 grid(BATCH / 64);   // 2048 blocks x 64 samples
    dim3 block(256);
    fbsnn_kernel<<<grid, block, 0, stream>>>(W0, b0, W1, b1, W2, b2, W3, b3,
                                             W4, b4, y0p, dW, out);
}

// Round 6
// 987.897 us; speedup vs baseline: 25.6907x; 1.1178x over previous
//
#include <hip/hip_runtime.h>

#define BATCH  131072
#define NSTEPS 100

typedef _Float16 half8  __attribute__((ext_vector_type(8)));
typedef _Float16 half2t __attribute__((ext_vector_type(2)));
typedef float    f32x4  __attribute__((ext_vector_type(4)));
typedef unsigned u32x4  __attribute__((ext_vector_type(4)));

__device__ __forceinline__ unsigned pkh2(float a, float b) {
    return __builtin_bit_cast(unsigned, __builtin_amdgcn_cvt_pkrtz(a, b));
}
__device__ __forceinline__ float loh(unsigned u) {
    half2t h = __builtin_bit_cast(half2t, u); return (float)h[0];
}
__device__ __forceinline__ float hih(unsigned u) {
    half2t h = __builtin_bit_cast(half2t, u); return (float)h[1];
}

// ---------------------------------------------------------------------------
// Fully in-register pipeline. Wave owns 16 samples; lane (c = l&15, g = l>>4)
// carries sample c. Per layer: 16 x mfma_f32_16x16x32_f16 (A = all 64x64
// weights, persistent VGPR f16; B = activations x|v, in registers).
// k-slot convention: B-frag (kt, qq, r) holds neuron n = 32kt+16qq+4g+r.
// With C layout row = 16mt+4g+r, lane g's C-quads ARE its next B-frags
// (bx0 = [mt0|mt1], bx1 = [mt2|mt3]) -> no LDS, no shuffles, no barriers.
// A-frags use the same k-permutation: afr[mt][kt][4qq+r] = W[16mt+c][n].
// L0 computes neurons n = 32kt+16qq+4g+r directly into frag slots; L3 folds
// the W4 dot with a 2-op butterfly (xor 16, 32). Waves fully independent.
// ---------------------------------------------------------------------------
extern "C" __global__ void __launch_bounds__(256, 2)
fbsnn_kernel(const float* __restrict__ W0, const float* __restrict__ b0,
             const float* __restrict__ W1, const float* __restrict__ b1,
             const float* __restrict__ W2, const float* __restrict__ b2,
             const float* __restrict__ W3, const float* __restrict__ b3,
             const float* __restrict__ W4, const float* __restrict__ b4,
             const float* __restrict__ y0p, const float* __restrict__ dW,
             float* __restrict__ slots)
{
    const int tid = threadIdx.x;
    const int l   = tid & 63;
    const int wu  = tid >> 6;
    const int c   = l & 15;          // sample col within wave (A row, B col, C col)
    const int g   = l >> 4;          // k-group / C row-group
    const int sample = blockIdx.x * 64 + wu * 16 + c;

    const float DT = 0.01f, SQDT = 0.1f;

    // ---- persistent A fragments (f16): afr[li][mt][kt][4qq+r] = W[16mt+c][32kt+16qq+4g+r]
    half8 afr[3][4][2];
    const float* Ws[3] = {W1, W2, W3};
    #pragma unroll
    for (int li = 0; li < 3; ++li)
      #pragma unroll
      for (int mt = 0; mt < 4; ++mt)
        #pragma unroll
        for (int kt = 0; kt < 2; ++kt)
          #pragma unroll
          for (int qq = 0; qq < 2; ++qq) {
            f32x4 w4v = *reinterpret_cast<const f32x4*>(
                Ws[li] + (16 * mt + c) * 64 + 32 * kt + 16 * qq + 4 * g);
            #pragma unroll
            for (int r = 0; r < 4; ++r)
                afr[li][mt][kt][4 * qq + r] = (_Float16)w4v[r];
          }

    // ---- packed per-lane constants (half2) ----
    unsigned bias_p[3][4][2];                 // rows 16mt+4g+r
    const float* bs[3] = {b1, b2, b3};
    #pragma unroll
    for (int li = 0; li < 3; ++li)
      #pragma unroll
      for (int mt = 0; mt < 4; ++mt) {
        f32x4 bv = *reinterpret_cast<const f32x4*>(bs[li] + 16 * mt + 4 * g);
        bias_p[li][mt][0] = pkh2(bv[0], bv[1]);
        bias_p[li][mt][1] = pkh2(bv[2], bv[3]);
      }
    unsigned w4_p[4][2];
    #pragma unroll
    for (int mt = 0; mt < 4; ++mt) {
        f32x4 wv = *reinterpret_cast<const f32x4*>(W4 + 16 * mt + 4 * g);
        w4_p[mt][0] = pkh2(wv[0], wv[1]);
        w4_p[mt][1] = pkh2(wv[2], wv[3]);
    }
    // L0 coeffs for neurons n0 = 32kt+16qq+4g (+0..3): qi = 2kt+qq
    unsigned l0wa[4][2], l0wb[4][2], l0b[4][2];
    #pragma unroll
    for (int qi = 0; qi < 4; ++qi) {
        int n0 = 32 * (qi >> 1) + 16 * (qi & 1) + 4 * g;
        f32x4 r0 = *reinterpret_cast<const f32x4*>(W0 + 2 * n0);      // wa0 wb0 wa1 wb1
        f32x4 r1 = *reinterpret_cast<const f32x4*>(W0 + 2 * n0 + 4);  // wa2 wb2 wa3 wb3
        f32x4 bb = *reinterpret_cast<const f32x4*>(b0 + n0);
        l0wa[qi][0] = pkh2(r0[0], r0[2]);  l0wa[qi][1] = pkh2(r1[0], r1[2]);
        l0wb[qi][0] = pkh2(r0[1], r0[3]);  l0wb[qi][1] = pkh2(r1[1], r1[3]);
        l0b[qi][0]  = pkh2(bb[0], bb[1]);  l0b[qi][1]  = pkh2(bb[2], bb[3]);
    }
    const float b4v = b4[0];

    float y = y0p[0];
    float t = 0.0f;
    float Y0 = 0.f, dY0 = 0.f, q0 = 0.f, Z0 = 0.f, dws = 0.f, loss = 0.f;

    #pragma unroll 1
    for (int s = 0; s <= NSTEPS; ++s) {
        float dwv = 0.0f;
        if (s < NSTEPS) dwv = dW[s * BATCH + sample];   // prefetch early

        // ============ layer 0: build B-frags directly in registers ============
        half8 BX[2], BV[2];
        #pragma unroll
        for (int kt = 0; kt < 2; ++kt) {
            u32x4 ux, uv;
            #pragma unroll
            for (int qq = 0; qq < 2; ++qq) {
                int qi = 2 * kt + qq;
                float sn[4], vv[4];
                #pragma unroll
                for (int h = 0; h < 2; ++h) {
                    float wa0 = loh(l0wa[qi][h]), wa1 = hih(l0wa[qi][h]);
                    float wb0 = loh(l0wb[qi][h]), wb1 = hih(l0wb[qi][h]);
                    float c00 = loh(l0b[qi][h]),  c01 = hih(l0b[qi][h]);
                    float z0 = fmaf(wa0, t, fmaf(wb0, y, c00));
                    float z1 = fmaf(wa1, t, fmaf(wb1, y, c01));
                    float s0, cc0, s1, cc1;
                    __sincosf(z0, &s0, &cc0);
                    __sincosf(z1, &s1, &cc1);
                    sn[2 * h] = s0; sn[2 * h + 1] = s1;
                    vv[2 * h] = cc0 * wb0; vv[2 * h + 1] = cc1 * wb1;
                }
                ux[2 * qq + 0] = pkh2(sn[0], sn[1]);
                ux[2 * qq + 1] = pkh2(sn[2], sn[3]);
                uv[2 * qq + 0] = pkh2(vv[0], vv[1]);
                uv[2 * qq + 1] = pkh2(vv[2], vv[3]);
            }
            BX[kt] = __builtin_bit_cast(half8, ux);
            BV[kt] = __builtin_bit_cast(half8, uv);
        }

        // ============ hidden layers 1..3, all in registers ============
        float Y1 = 0.f, dY1 = 0.f;
        #pragma unroll
        for (int li = 0; li < 3; ++li) {
            f32x4 ax[4], av[4];
            #pragma unroll
            for (int mt = 0; mt < 4; ++mt) {
                f32x4 ci;
                ci[0] = loh(bias_p[li][mt][0]); ci[1] = hih(bias_p[li][mt][0]);
                ci[2] = loh(bias_p[li][mt][1]); ci[3] = hih(bias_p[li][mt][1]);
                f32x4 a = __builtin_amdgcn_mfma_f32_16x16x32_f16(afr[li][mt][0], BX[0], ci, 0, 0, 0);
                a = __builtin_amdgcn_mfma_f32_16x16x32_f16(afr[li][mt][1], BX[1], a, 0, 0, 0);
                ax[mt] = a;
                f32x4 v = {0.f, 0.f, 0.f, 0.f};
                v = __builtin_amdgcn_mfma_f32_16x16x32_f16(afr[li][mt][0], BV[0], v, 0, 0, 0);
                v = __builtin_amdgcn_mfma_f32_16x16x32_f16(afr[li][mt][1], BV[1], v, 0, 0, 0);
                av[mt] = v;
            }
            if (li < 2) {
                u32x4 nx[2], nv[2];
                #pragma unroll
                for (int mt = 0; mt < 4; ++mt) {
                    float sn[4], vv[4];
                    #pragma unroll
                    for (int r = 0; r < 4; ++r) {
                        float s1, c1;
                        __sincosf(ax[mt][r], &s1, &c1);
                        sn[r] = s1; vv[r] = c1 * av[mt][r];
                    }
                    nx[mt >> 1][2 * (mt & 1) + 0] = pkh2(sn[0], sn[1]);
                    nx[mt >> 1][2 * (mt & 1) + 1] = pkh2(sn[2], sn[3]);
                    nv[mt >> 1][2 * (mt & 1) + 0] = pkh2(vv[0], vv[1]);
                    nv[mt >> 1][2 * (mt & 1) + 1] = pkh2(vv[2], vv[3]);
                }
                BX[0] = __builtin_bit_cast(half8, nx[0]);
                BX[1] = __builtin_bit_cast(half8, nx[1]);
                BV[0] = __builtin_bit_cast(half8, nv[0]);
                BV[1] = __builtin_bit_cast(half8, nv[1]);
            } else {
                // fold W4 dot; butterfly over g (rows) -> all lanes get Y,dY
                float sx = 0.f, sv = 0.f;
                #pragma unroll
                for (int mt = 0; mt < 4; ++mt) {
                    float w0 = loh(w4_p[mt][0]), w1 = hih(w4_p[mt][0]);
                    float w2 = loh(w4_p[mt][1]), w3 = hih(w4_p[mt][1]);
                    float wv[4] = {w0, w1, w2, w3};
                    #pragma unroll
                    for (int r = 0; r < 4; ++r) {
                        float s1, c1;
                        __sincosf(ax[mt][r], &s1, &c1);
                        sx = fmaf(wv[r], s1, sx);
                        sv = fmaf(wv[r], c1 * av[mt][r], sv);
                    }
                }
                sx += __shfl_xor(sx, 16); sx += __shfl_xor(sx, 32);
                sv += __shfl_xor(sv, 16); sv += __shfl_xor(sv, 32);
                Y1  = sx + b4v;
                dY1 = sv;
            }
        }

        // ============ trajectory / loss ============
        if (s > 0) {
            float Yt = Y0 - q0 * q0 * DT + Z0 * dws;
            float d  = Y1 - Yt;
            loss += d * d;
        }
        Y0 = Y1; dY0 = dY1;
        if (s < NSTEPS) {
            Z0  = 0.5f * dY0;
            q0  = -dY0;                 // -0.5*Z0/SIG^2, exact (powers of 2)
            dws = dwv * SQDT;
            y   = y + q0 * DT + 0.5f * dws;
            t   = t + DT;
        }
    }

    // terminal: (YN - yN^2)^2 + (dYN - 2*yN)^2
    float d1 = Y0 - y * y;
    float d2 = dY0 - 2.0f * y;
    loss += d1 * d1 + d2 * d2;

    // lane-redundancy mask (4 g-lanes share a sample) + wave butterfly
    float lv = (g == 0) ? loss : 0.0f;
    #pragma unroll
    for (int off = 1; off < 64; off <<= 1)
        lv += __shfl_xor(lv, off);
    if (l == 0)
        atomicAdd(&slots[(blockIdx.x * 4 + wu) & 255], lv);
}

extern "C" __global__ void finish_kernel(const float* __restrict__ slots,
                                         float* __restrict__ out) {
    int l = threadIdx.x;   // 64 threads
    float v = slots[l] + slots[64 + l] + slots[128 + l] + slots[192 + l];
    #pragma unroll
    for (int off = 1; off < 64; off <<= 1)
        v += __shfl_xor(v, off);
    if (l == 0) out[0] = v * (1.0f / (float)BATCH);
}

extern "C" void kernel_launch(void* const* d_in, const int* in_sizes, int n_in,
                              void* d_out, int out_size, void* d_ws, size_t ws_size,
                              hipStream_t stream) {
    const float* W0  = (const float*)d_in[0];
    const float* b0  = (const float*)d_in[1];
    const float* W1  = (const float*)d_in[2];
    const float* b1  = (const float*)d_in[3];
    const float* W2  = (const float*)d_in[4];
    const float* b2  = (const float*)d_in[5];
    const float* W3  = (const float*)d_in[6];
    const float* b3  = (const float*)d_in[7];
    const float* W4  = (const float*)d_in[8];
    const float* b4  = (const float*)d_in[9];
    const float* y0p = (const float*)d_in[10];
    const float* dW  = (const float*)d_in[11];
    float* slots = (float*)d_ws;

    hipMemsetAsync(d_ws, 0, 256 * sizeof(float), stream);

    dim3 grid(BATCH / 64);   // 2048 blocks x 4 independent waves (16 samples each)
    dim3 block(256);
    fbsnn_kernel<<<grid, block, 0, stream>>>(W0, b0, W1, b1, W2, b2, W3, b3,
                                             W4, b4, y0p, dW, slots);
    finish_kernel<<<1, 64, 0, stream>>>(slots, (float*)d_out);
}